// Round 2
// baseline (26.511 us; speedup 1.0000x reference)
//
#include <hip/hip_runtime.h>
#include <hip/hip_bf16.h>

#define BATCH 64
#define DIM 64
#define BANKN 131072

typedef __bf16 bf16x8 __attribute__((ext_vector_type(8)));
typedef float f32x16 __attribute__((ext_vector_type(16)));

__device__ inline bf16x8 pack_bf16x8(float4 a, float4 b) {
  bf16x8 r;
  r[0] = (__bf16)a.x; r[1] = (__bf16)a.y; r[2] = (__bf16)a.z; r[3] = (__bf16)a.w;
  r[4] = (__bf16)b.x; r[5] = (__bf16)b.y; r[6] = (__bf16)b.z; r[7] = (__bf16)b.w;
  return r;
}

// One wave computes a 64(m) x 32(n) output tile:
//   C = E[64x64] * bank^T[64 x 131072] via 2 m-tiles x 4 k-steps of
//   v_mfma_f32_32x32x16_bf16, then dist = sqrt(||e||^2 + ||b||^2 - 2C).
// __launch_bounds__(256, 4): 4 waves/EU -> 4 blocks/CU co-resident (VGPR<=128),
// so the whole 1024-block grid runs as ONE generation.
__global__ __launch_bounds__(256, 4) void mb_dist(const float* __restrict__ emb,
                                                  const float* __restrict__ bank,
                                                  float* __restrict__ out) {
  __shared__ float qn_lds[BATCH];

  const int tid  = threadIdx.x;
  const int lane = tid & 63;
  const int wave = tid >> 6;
  const int lr   = lane & 31;   // row-in-tile (A) / col (B,C)
  const int lh   = lane >> 5;   // k-group half

  // ---- issue the HBM-critical bank loads FIRST ----
  // b[ks][j] = bank[n0 + lr][ks*16 + lh*8 + j]
  const int n0 = (blockIdx.x * 4 + wave) * 32;
  const float* brow = bank + (size_t)(n0 + lr) * DIM;
  float4 bv[8];
#pragma unroll
  for (int ks = 0; ks < 4; ++ks) {
    const float4* p = (const float4*)(brow + ks * 16 + lh * 8);
    bv[2 * ks]     = p[0];
    bv[2 * ks + 1] = p[1];
  }

  // ---- qn[m] = ||e_m||^2 (exact fp32) into LDS; threads 0..63 ----
  if (tid < BATCH) {
    const float4* er = (const float4*)(emb + tid * DIM);
    float s = 0.f;
#pragma unroll
    for (int i = 0; i < DIM / 4; ++i) {
      float4 v = er[i];
      s = fmaf(v.x, v.x, s); s = fmaf(v.y, v.y, s);
      s = fmaf(v.z, v.z, s); s = fmaf(v.w, v.w, s);
    }
    qn_lds[tid] = s;
  }

  // ---- B fragments + ||b||^2 partial (exact fp32) ----
  float bsum = 0.f;
  bf16x8 bfr[4];
#pragma unroll
  for (int ks = 0; ks < 4; ++ks) {
    float4 v0 = bv[2 * ks], v1 = bv[2 * ks + 1];
    bsum = fmaf(v0.x, v0.x, bsum); bsum = fmaf(v0.y, v0.y, bsum);
    bsum = fmaf(v0.z, v0.z, bsum); bsum = fmaf(v0.w, v0.w, bsum);
    bsum = fmaf(v1.x, v1.x, bsum); bsum = fmaf(v1.y, v1.y, bsum);
    bsum = fmaf(v1.z, v1.z, bsum); bsum = fmaf(v1.w, v1.w, bsum);
    bfr[ks] = pack_bf16x8(v0, v1);
  }
  // partner lane (lh^1) holds the other 32 elements of this row
  float bn = bsum + __shfl_xor(bsum, 32);

  // ---- MFMA per m-tile; A fragments built per tile to cap live VGPRs ----
  // a[ks][j] = E[mt*32 + lr][ks*16 + lh*8 + j]  (emb is L1-hot, 16 KB)
  f32x16 acc0, acc1;
#pragma unroll
  for (int i = 0; i < 16; ++i) { acc0[i] = 0.f; acc1[i] = 0.f; }
  {
    bf16x8 a[4];
#pragma unroll
    for (int ks = 0; ks < 4; ++ks) {
      const float4* r = (const float4*)(emb + lr * DIM + ks * 16 + lh * 8);
      a[ks] = pack_bf16x8(r[0], r[1]);
    }
#pragma unroll
    for (int ks = 0; ks < 4; ++ks)
      acc0 = __builtin_amdgcn_mfma_f32_32x32x16_bf16(a[ks], bfr[ks], acc0, 0, 0, 0);
  }
  {
    bf16x8 a[4];
#pragma unroll
    for (int ks = 0; ks < 4; ++ks) {
      const float4* r = (const float4*)(emb + (32 + lr) * DIM + ks * 16 + lh * 8);
      a[ks] = pack_bf16x8(r[0], r[1]);
    }
#pragma unroll
    for (int ks = 0; ks < 4; ++ks)
      acc1 = __builtin_amdgcn_mfma_f32_32x32x16_bf16(a[ks], bfr[ks], acc1, 0, 0, 0);
  }

  __syncthreads();  // qn_lds ready

  // ---- epilogue: C/D layout col = lane&31, row = (reg&3)+8*(reg>>2)+4*lh ----
  const int ncol = n0 + lr;
  float* ocol = out + ncol;
#pragma unroll
  for (int reg = 0; reg < 16; ++reg) {
    const int rr = (reg & 3) + 8 * (reg >> 2) + 4 * lh;
    {
      float d2 = fmaf(-2.f, acc0[reg], qn_lds[rr] + bn);
      ocol[(size_t)rr * BANKN] = sqrtf(fmaxf(d2, 0.f));
    }
    {
      float d2 = fmaf(-2.f, acc1[reg], qn_lds[32 + rr] + bn);
      ocol[(size_t)(32 + rr) * BANKN] = sqrtf(fmaxf(d2, 0.f));
    }
  }
}

extern "C" void kernel_launch(void* const* d_in, const int* in_sizes, int n_in,
                              void* d_out, int out_size, void* d_ws, size_t ws_size,
                              hipStream_t stream) {
  const float* emb  = (const float*)d_in[0];
  const float* bank = (const float*)d_in[1];
  float* out = (float*)d_out;
  // 1024 blocks x 256 threads; each block covers 4 waves x 32 bank rows = 128 rows
  mb_dist<<<dim3(BANKN / 128), dim3(256), 0, stream>>>(emb, bank, out);
}

// Round 3
// 25.637 us; speedup vs baseline: 1.0341x; 1.0341x over previous
//
#include <hip/hip_runtime.h>
#include <hip/hip_bf16.h>

#define BATCH 64
#define DIM 64
#define BANKN 131072

typedef __bf16 bf16x8 __attribute__((ext_vector_type(8)));
typedef float f32x16 __attribute__((ext_vector_type(16)));

__device__ inline bf16x8 pack_bf16x8(float4 a, float4 b) {
  bf16x8 r;
  r[0] = (__bf16)a.x; r[1] = (__bf16)a.y; r[2] = (__bf16)a.z; r[3] = (__bf16)a.w;
  r[4] = (__bf16)b.x; r[5] = (__bf16)b.y; r[6] = (__bf16)b.z; r[7] = (__bf16)b.w;
  return r;
}

// One wave computes a 64(m) x 32(n) tile of C = E * bank^T via 2x4
// v_mfma_f32_32x32x16_bf16, dist = sqrt(||e||^2 + ||b||^2 - 2C).
// Output is transposed through LDS so every global store is a 512-B
// contiguous segment per 32-lane half (vs 128-B scattered before).
__global__ __launch_bounds__(256, 4) void mb_dist(const float* __restrict__ emb,
                                                  const float* __restrict__ bank,
                                                  float* __restrict__ out) {
  __shared__ float qn_lds[BATCH];
  __shared__ float s_out[BATCH][128];  // 32 KB block output tile

  const int tid  = threadIdx.x;
  const int lane = tid & 63;
  const int wave = tid >> 6;
  const int lr   = lane & 31;   // row-in-tile (A) / col (B,C)
  const int lh   = lane >> 5;   // k-group half

  // ---- HBM-critical bank loads first ----
  const int n0 = (blockIdx.x * 4 + wave) * 32;
  const float* brow = bank + (size_t)(n0 + lr) * DIM;
  float4 bv[8];
#pragma unroll
  for (int ks = 0; ks < 4; ++ks) {
    const float4* p = (const float4*)(brow + ks * 16 + lh * 8);
    bv[2 * ks]     = p[0];
    bv[2 * ks + 1] = p[1];
  }

  // ---- qn[m] = ||e_m||^2 (exact fp32); threads 0..63 ----
  if (tid < BATCH) {
    const float4* er = (const float4*)(emb + tid * DIM);
    float s = 0.f;
#pragma unroll
    for (int i = 0; i < DIM / 4; ++i) {
      float4 v = er[i];
      s = fmaf(v.x, v.x, s); s = fmaf(v.y, v.y, s);
      s = fmaf(v.z, v.z, s); s = fmaf(v.w, v.w, s);
    }
    qn_lds[tid] = s;
  }

  // ---- B fragments + ||b||^2 partial (exact fp32) ----
  float bsum = 0.f;
  bf16x8 bfr[4];
#pragma unroll
  for (int ks = 0; ks < 4; ++ks) {
    float4 v0 = bv[2 * ks], v1 = bv[2 * ks + 1];
    bsum = fmaf(v0.x, v0.x, bsum); bsum = fmaf(v0.y, v0.y, bsum);
    bsum = fmaf(v0.z, v0.z, bsum); bsum = fmaf(v0.w, v0.w, bsum);
    bsum = fmaf(v1.x, v1.x, bsum); bsum = fmaf(v1.y, v1.y, bsum);
    bsum = fmaf(v1.z, v1.z, bsum); bsum = fmaf(v1.w, v1.w, bsum);
    bfr[ks] = pack_bf16x8(v0, v1);
  }
  float bn = bsum + __shfl_xor(bsum, 32);  // partner lane has other 32 elems

  // ---- MFMA; A fragments per m-tile (emb L1/L2-hot) ----
  f32x16 acc0, acc1;
#pragma unroll
  for (int i = 0; i < 16; ++i) { acc0[i] = 0.f; acc1[i] = 0.f; }
  {
    bf16x8 a[4];
#pragma unroll
    for (int ks = 0; ks < 4; ++ks) {
      const float4* r = (const float4*)(emb + lr * DIM + ks * 16 + lh * 8);
      a[ks] = pack_bf16x8(r[0], r[1]);
    }
#pragma unroll
    for (int ks = 0; ks < 4; ++ks)
      acc0 = __builtin_amdgcn_mfma_f32_32x32x16_bf16(a[ks], bfr[ks], acc0, 0, 0, 0);
  }
  {
    bf16x8 a[4];
#pragma unroll
    for (int ks = 0; ks < 4; ++ks) {
      const float4* r = (const float4*)(emb + (32 + lr) * DIM + ks * 16 + lh * 8);
      a[ks] = pack_bf16x8(r[0], r[1]);
    }
#pragma unroll
    for (int ks = 0; ks < 4; ++ks)
      acc1 = __builtin_amdgcn_mfma_f32_32x32x16_bf16(a[ks], bfr[ks], acc1, 0, 0, 0);
  }

  __syncthreads();  // qn_lds ready; s_out not yet touched

  // ---- epilogue into LDS tile ----
  // C/D layout: col = lane&31, row = (reg&3) + 8*(reg>>2) + 4*lh
  // ds_write banks: bank = lr for both halves -> 2-way alias (free, m136)
  const int cloc = wave * 32 + lr;
#pragma unroll
  for (int reg = 0; reg < 16; ++reg) {
    const int rr = (reg & 3) + 8 * (reg >> 2) + 4 * lh;
    s_out[rr][cloc]      = sqrtf(fmaxf(fmaf(-2.f, acc0[reg], qn_lds[rr]      + bn), 0.f));
    s_out[32 + rr][cloc] = sqrtf(fmaxf(fmaf(-2.f, acc1[reg], qn_lds[32 + rr] + bn), 0.f));
  }

  __syncthreads();

  // ---- cooperative wide stores: 512-B contiguous per 32-lane half ----
  const int c0   = blockIdx.x * 128;
  const int srow = tid >> 5;   // 0..7
  const int scg  = tid & 31;   // 16-B column group
#pragma unroll
  for (int it = 0; it < 8; ++it) {
    const int r = it * 8 + srow;
    float4 v = *(const float4*)&s_out[r][scg * 4];
    *(float4*)(out + (size_t)r * BANKN + c0 + scg * 4) = v;
  }
}

extern "C" void kernel_launch(void* const* d_in, const int* in_sizes, int n_in,
                              void* d_out, int out_size, void* d_ws, size_t ws_size,
                              hipStream_t stream) {
  const float* emb  = (const float*)d_in[0];
  const float* bank = (const float*)d_in[1];
  float* out = (float*)d_out;
  // 1024 blocks x 256 threads; each block: 4 waves x 32 bank rows = 128 rows
  mb_dist<<<dim3(BANKN / 128), dim3(256), 0, stream>>>(emb, bank, out);
}

// Round 4
// 24.496 us; speedup vs baseline: 1.0823x; 1.0466x over previous
//
#include <hip/hip_runtime.h>
#include <hip/hip_bf16.h>

#define BATCH 64
#define DIM 64
#define BANKN 131072

typedef __bf16 bf16x8 __attribute__((ext_vector_type(8)));
typedef __bf16 bf16x4 __attribute__((ext_vector_type(4)));
typedef float f32x16 __attribute__((ext_vector_type(16)));

__device__ inline bf16x8 pack_bf16x8(float4 a, float4 b) {
  bf16x8 r;
  r[0] = (__bf16)a.x; r[1] = (__bf16)a.y; r[2] = (__bf16)a.z; r[3] = (__bf16)a.w;
  r[4] = (__bf16)b.x; r[5] = (__bf16)b.y; r[6] = (__bf16)b.z; r[7] = (__bf16)b.w;
  return r;
}

// C = E[64x64] * bank^T, dist = sqrt(||e||^2 + ||b||^2 - 2C).
// v4: ALL global accesses lane-contiguous (front-end divergence fix);
// fragment layouts produced via LDS redistribution.
//  - bank: 8x contiguous 1KB loads -> XOR-swizzled LDS -> fragment ds_read_b128
//  - emb:  staged once/block to bf16 fragment-linear LDS; qn fused in fp32
//  - out:  per-wave LDS transpose (reusing bank tile region) -> 128B-row stores
__global__ __launch_bounds__(256, 3) void mb_dist(const float* __restrict__ emb,
                                                  const float* __restrict__ bank,
                                                  float* __restrict__ out) {
  // LDS: emb fragments (bf16) 8KB + qn 256B + bn 512B + per-wave bank/out tile 32KB
  __shared__ __align__(16) unsigned char s_emb[8192];
  __shared__ float s_qn[BATCH];
  __shared__ float s_bn[4 * 32];
  __shared__ __align__(16) float s_bank[4][2048];

  const int tid  = threadIdx.x;
  const int lane = tid & 63;
  const int wave = tid >> 6;
  const int lr   = lane & 31;        // fragment row (bank) / C col
  const int lh   = lane >> 5;        // k-half
  const int q16  = (lane >> 4) & 3;  // 16-lane group id
  const int s16  = lane & 15;        // index within 16-lane group

  // ---- 1) bank tile: 8 fully-contiguous 1-KB loads (HBM-critical, first) ----
  const int n0 = (blockIdx.x * 4 + wave) * 32;
  const float4* wbase = (const float4*)(bank + (size_t)n0 * DIM);
  float4 bv[8];
#pragma unroll
  for (int i = 0; i < 8; ++i) bv[i] = wbase[i * 64 + lane];

  // ---- 2) emb staging: 4 contiguous 4-KB loads across the block ----
  float4 ev[4];
#pragma unroll
  for (int j = 0; j < 4; ++j) ev[j] = ((const float4*)emb)[j * 256 + tid];

  // qn (exact fp32): 16 consecutive lanes hold one emb row's 16 granules
#pragma unroll
  for (int j = 0; j < 4; ++j) {
    float4 v = ev[j];
    float sq = fmaf(v.x, v.x, fmaf(v.y, v.y, fmaf(v.z, v.z, v.w * v.w)));
    sq += __shfl_xor(sq, 1); sq += __shfl_xor(sq, 2);
    sq += __shfl_xor(sq, 4); sq += __shfl_xor(sq, 8);
    if (s16 == 0) s_qn[j * 16 + wave * 4 + q16] = sq;
  }

  // emb -> bf16, scatter to fragment-linear layout:
  // byte = ((mt*4+ks)*2+lh)*512 + lr*16 + p*8  for src granule (row, colg),
  // colg bits: [3:2]=ks, [1]=lh, [0]=p
#pragma unroll
  for (int j = 0; j < 4; ++j) {
    const int gsrc = j * 256 + tid;
    const int row = gsrc >> 4, colg = gsrc & 15;
    const int mt = row >> 5, r5 = row & 31;
    const int ks = colg >> 2, lhh = (colg >> 1) & 1, p = colg & 1;
    bf16x4 c;
    c[0] = (__bf16)ev[j].x; c[1] = (__bf16)ev[j].y;
    c[2] = (__bf16)ev[j].z; c[3] = (__bf16)ev[j].w;
    const int off = ((mt * 4 + ks) * 2 + lhh) * 512 + r5 * 16 + p * 8;
    *(bf16x4*)(s_emb + off) = c;
  }

  // ---- 3) bank -> LDS (XOR-swizzled, conflict-free) + ||b||^2 in fp32 ----
  char* const myTile = (char*)&s_bank[wave][0];
#pragma unroll
  for (int i = 0; i < 8; ++i) {
    const int g = i * 64 + lane;
    const int off = (g * 16) ^ (((g >> 4) & 7) << 4);
    *(float4*)(myTile + off) = bv[i];
    float4 v = bv[i];
    float sq = fmaf(v.x, v.x, fmaf(v.y, v.y, fmaf(v.z, v.z, v.w * v.w)));
    sq += __shfl_xor(sq, 1); sq += __shfl_xor(sq, 2);
    sq += __shfl_xor(sq, 4); sq += __shfl_xor(sq, 8);
    if (s16 == 0) s_bn[wave * 32 + i * 4 + q16] = sq;
  }

  __syncthreads();  // s_emb + s_qn ready (s_bank/s_bn are same-wave, in-order)

  const float bnv = s_bn[wave * 32 + lr];

  // ---- 4) bank fragments from swizzled LDS (row = lr) ----
  bf16x8 bfr[4];
#pragma unroll
  for (int ks = 0; ks < 4; ++ks) {
    const int g0 = lr * 16 + ks * 4 + lh * 2;
    const int swz = (lr & 7) << 4;
    float4 lo = *(const float4*)(myTile + ((g0 * 16) ^ swz));
    float4 hi = *(const float4*)(myTile + (((g0 + 1) * 16) ^ swz));
    bfr[ks] = pack_bf16x8(lo, hi);
  }

  // ---- 5) MFMA: A fragments are single conflict-free b128 reads ----
  f32x16 acc0, acc1;
#pragma unroll
  for (int i = 0; i < 16; ++i) { acc0[i] = 0.f; acc1[i] = 0.f; }
#pragma unroll
  for (int ks = 0; ks < 4; ++ks) {
    bf16x8 a = *(const bf16x8*)(s_emb + (0 * 4 + ks) * 1024 + lane * 16);
    acc0 = __builtin_amdgcn_mfma_f32_32x32x16_bf16(a, bfr[ks], acc0, 0, 0, 0);
  }
#pragma unroll
  for (int ks = 0; ks < 4; ++ks) {
    bf16x8 a = *(const bf16x8*)(s_emb + (1 * 4 + ks) * 1024 + lane * 16);
    acc1 = __builtin_amdgcn_mfma_f32_32x32x16_bf16(a, bfr[ks], acc1, 0, 0, 0);
  }

  // ---- 6) epilogue into own tile region as [64 rows][32 cols] f32 ----
  // (safe WAR: epilogue values depend on MFMA which waited on fragment reads)
  float* otile = &s_bank[wave][0];
#pragma unroll
  for (int reg = 0; reg < 16; ++reg) {
    const int rr = (reg & 3) + 8 * (reg >> 2) + 4 * lh;
    otile[rr * 32 + lr] =
        sqrtf(fmaxf(fmaf(-2.f, acc0[reg], s_qn[rr] + bnv), 0.f));
    otile[(32 + rr) * 32 + lr] =
        sqrtf(fmaxf(fmaf(-2.f, acc1[reg], s_qn[32 + rr] + bnv), 0.f));
  }

  // ---- 7) stores: 8 instrs, each = 8 output rows x 128-B contiguous ----
#pragma unroll
  for (int j = 0; j < 8; ++j) {
    const int r = j * 8 + (lane >> 3);
    float4 v = *(const float4*)(otile + r * 32 + (lane & 7) * 4);
    *(float4*)(out + (size_t)r * BANKN + n0 + (lane & 7) * 4) = v;
  }
}

extern "C" void kernel_launch(void* const* d_in, const int* in_sizes, int n_in,
                              void* d_out, int out_size, void* d_ws, size_t ws_size,
                              hipStream_t stream) {
  const float* emb  = (const float*)d_in[0];
  const float* bank = (const float*)d_in[1];
  float* out = (float*)d_out;
  mb_dist<<<dim3(BANKN / 128), dim3(256), 0, stream>>>(emb, bank, out);
}